// Round 6
// baseline (2841.731 us; speedup 1.0000x reference)
//
#include <hip/hip_runtime.h>
#include <hip/hip_bf16.h>

// ---------------- workspace layout v6 (total 74,842,112 bytes) ----------------
// float indices into (float*)d_ws:
#define FC0_F   0        // fc0_w [64][3]
#define FC0B_F  192      // fc0_b [64]
#define PWF_F   256      // pw_w transposed [4][i][o] (16384)
#define PWB_F   16640    // pw_b [4][64]
#define FC1T_F  16896    // fc1_w transposed [64 i][128 f] (8192)
#define FC1B_F  25088    // fc1_b [128]
#define FC2_F   25216    // fc2_w [128]
#define FC2B_F  25344    // fc2_b [1]
#define PHW_F   25408    // phW [256 w][12 ky][2] (6144)
#define PHH_F   31552    // phH [256 x][24 kx][2] (12288) -> end 43840
#define FLAG_F  44032    // 1.0 => inputs f32
#define SN_T    44033    // NaN flags: tables, G, Fo, HB
#define SN_G    44034
#define SN_FO   44035
#define SN_HB   44036
// bf16 element indices into (__hip_bfloat16*)d_ws:
#define HB_OFF_U  131072     // h [8][256][256][64]  (33554432 elems)
#define G_OFF_U   33685504   // G [8][12][256][64][2] (3145728 elems)
// float index for Fo:
#define FO_OFF_F  18415616   // Fo [8][12][24][64][2] f32 (294912)
#define WS_NEED   74842112
#define NTAB 43840

__device__ __forceinline__ float rdw(const __hip_bfloat16* h, const float* f,
                                     long i, int isf32) {
  return isf32 ? f[i] : __bfloat162float(h[i]);
}

// ---------------- fill output with a code ----------------
__global__ __launch_bounds__(256) void kf6_fill(__hip_bfloat16* outH, float code) {
  outH[(size_t)blockIdx.x * 256 + threadIdx.x] = __float2bfloat16(code);
}

// ---------------- dtype detect on X + flag init ----------------
__global__ __launch_bounds__(64) void kd6_detect(const unsigned short* Xh, float* Wf) {
  if (threadIdx.x == 0 && blockIdx.x == 0) {
    int ok = 1;
    for (int k = 0; k < 128; ++k) {
      unsigned short u = Xh[2 * k];        // even ushorts: bf16 elems OR f32 low-halves
      unsigned e = (u >> 7) & 0xFF;
      if (!(u == 0 || (e >= 0x60 && e <= 0x88))) ok = 0;
    }
    Wf[FLAG_F] = ok ? 0.0f : 1.0f;
    Wf[SN_T] = 0.0f; Wf[SN_G] = 0.0f; Wf[SN_FO] = 0.0f; Wf[SN_HB] = 0.0f;
  }
}

// ---------------- tables ----------------
__global__ __launch_bounds__(256) void kt6_tables(
    const __hip_bfloat16* f0h, const float* f0f,
    const __hip_bfloat16* f0bh, const float* f0bf,
    const __hip_bfloat16* pwh, const float* pwf,
    const __hip_bfloat16* pwbh, const float* pwbf,
    const __hip_bfloat16* f1h, const float* f1f,
    const __hip_bfloat16* f1bh, const float* f1bf,
    const __hip_bfloat16* f2h, const float* f2f,
    const __hip_bfloat16* f2bh, const float* f2bf,
    float* Wf) {
  const int isf32 = (Wf[FLAG_F] != 0.0f);
  const int stride = gridDim.x * blockDim.x;
  for (int n0 = blockIdx.x * blockDim.x + threadIdx.x; n0 < NTAB; n0 += stride) {
    int n = n0;
    if (n < 192) { Wf[FC0_F + n] = rdw(f0h, f0f, n, isf32); continue; }
    n -= 192;
    if (n < 64)  { Wf[FC0B_F + n] = rdw(f0bh, f0bf, n, isf32); continue; }
    n -= 64;
    if (n < 16384) { int l = n >> 12, i = (n >> 6) & 63, o = n & 63;
      Wf[PWF_F + n] = rdw(pwh, pwf, (l*64 + o)*64 + i, isf32); continue; }
    n -= 16384;
    if (n < 256) { Wf[PWB_F + n] = rdw(pwbh, pwbf, n, isf32); continue; }
    n -= 256;
    if (n < 8192) { int i = n >> 7, f = n & 127;
      Wf[FC1T_F + n] = rdw(f1h, f1f, f*64 + i, isf32); continue; }
    n -= 8192;
    if (n < 128) { Wf[FC1B_F + n] = rdw(f1bh, f1bf, n, isf32); continue; }
    n -= 128;
    if (n < 128) { Wf[FC2_F + n] = rdw(f2h, f2f, n, isf32); continue; }
    n -= 128;
    if (n < 1)   { Wf[FC2B_F + n] = rdw(f2bh, f2bf, 0, isf32); continue; }
    n -= 1;
    if (n < 6144) { int w = n / 24, r = n % 24, ky = r >> 1, part = r & 1;
      int idx = (w * ky) & 255; float a = idx * (1.0f/128.0f);
      Wf[PHW_F + n] = part ? sinpif(a) : cospif(a); continue; }
    n -= 6144;
    { int x = n / 48, r = n % 48, kx = r >> 1, part = r & 1;
      int kxa = (kx < 12) ? kx : kx + 232;          // 244..255 = negative H rows
      int idx = (x * kxa) & 255; float a = idx * (1.0f/128.0f);
      Wf[PHH_F + n] = part ? sinpif(a) : cospif(a); }
  }
}

// ---------------- forward DFT along W of the row in LDS -> G ----------------
// hrow layout (swizzled): hrow[c*256 + ((w+c)&255)]
__device__ void gstep_v6(const float* Wf, __hip_bfloat16* G,
                         __hip_bfloat16* hrow, float* pbuf, int b, int x) {
  const int t = threadIdx.x;
  const int c = t & 63, q = t >> 6;
  float aR[12], aI[12];
#pragma unroll
  for (int k = 0; k < 12; ++k) { aR[k] = 0.0f; aI[k] = 0.0f; }
  for (int j = 0; j < 64; ++j) {
    int w = q*64 + j;                              // wave-uniform
    float hv = __bfloat162float(hrow[c*256 + ((w + c) & 255)]);
    const float* ph = Wf + PHW_F + w*24;
#pragma unroll
    for (int k = 0; k < 12; ++k) {
      aR[k] += hv * ph[2*k];
      aI[k] -= hv * ph[2*k + 1];
    }
  }
  __syncthreads();
#pragma unroll
  for (int k = 0; k < 12; ++k) {
    pbuf[q*1600 + c*25 + 2*k]     = aR[k];
    pbuf[q*1600 + c*25 + 2*k + 1] = aI[k];
  }
  __syncthreads();
#pragma unroll
  for (int j = 0; j < 6; ++j) {
    int idx = j*256 + t;                      // 1536 = ky*128 + cc*2 + part
    int part = idx & 1, cc = (idx >> 1) & 63, ky = idx >> 7;
    int m = 2*ky + part;
    float s = pbuf[cc*25 + m] + pbuf[1600 + cc*25 + m]
            + pbuf[3200 + cc*25 + m] + pbuf[4800 + cc*25 + m];
    G[(size_t)((b*12 + ky)*256 + x)*128 + cc*2 + part] = __float2bfloat16(s);
  }
}

// ---------------- lift: fc0 -> HB + LDS row, then DFT-W -> G ----------------
__global__ __launch_bounds__(256) void kl6_lift(const __hip_bfloat16* Xh,
                                                const float* Xf,
                                                const float* Wf,
                                                __hip_bfloat16* HB,
                                                __hip_bfloat16* G) {
  __shared__ __hip_bfloat16 hrow[16384];
  __shared__ float pbuf[6400];
  const int b = blockIdx.x >> 8, x = blockIdx.x & 255;
  const int w = threadIdx.x;
  const int isf32 = (Wf[FLAG_F] != 0.0f);
  float xv = rdw(Xh, Xf, (size_t)(b*256 + x)*256 + w, isf32);
  float gx = x * (1.0f/255.0f), gy = w * (1.0f/255.0f);
  __hip_bfloat16* hb = HB + ((size_t)(b*256 + x)*256 + w)*64;
#pragma unroll
  for (int c = 0; c < 64; ++c) {
    float hv = xv*Wf[FC0_F + c*3] + gx*Wf[FC0_F + c*3 + 1]
             + gy*Wf[FC0_F + c*3 + 2] + Wf[FC0B_F + c];
    __hip_bfloat16 hvb = __float2bfloat16(hv);
    hrow[c*256 + ((w + c) & 255)] = hvb;
    hb[c] = hvb;
  }
  __syncthreads();
  gstep_v6(Wf, G, hrow, pbuf, b, x);
}

// ---------------- spectral: DFT-H + channel mix (raw w1/w2) -> Fo ----------------
__global__ __launch_bounds__(256) void ks6_spec(const float* Wf,
                                                const __hip_bfloat16* G,
                                                const __hip_bfloat16* w1h, const float* w1f,
                                                const __hip_bfloat16* w2h, const float* w2f,
                                                float* Fo, int l) {
  __shared__ float lds[15616];
  float* Fbuf  = lds;          // 3072: F[kx][i][2]
  float* pbufA = lds + 3072;   // 12544 partial sums
  const int b = blockIdx.x / 12, ky = blockIdx.x % 12;
  const int t = threadIdx.x;
  const int isf32 = (Wf[FLAG_F] != 0.0f);
  // A: F[kx,i] = sum_x G[i,x] e^{-i 2pi x kxa/256}
  {
    const __hip_bfloat16* Gp = G + (size_t)(b*12 + ky)*32768;   // [x][i][2]
    const int i = t & 63, q = t >> 6;
    float fr[24], fi[24];
#pragma unroll
    for (int k = 0; k < 24; ++k) { fr[k] = 0.0f; fi[k] = 0.0f; }
    for (int j = 0; j < 64; ++j) {
      int x = q*64 + j;                            // wave-uniform
      float gr = __bfloat162float(Gp[x*128 + i*2]);
      float gi = __bfloat162float(Gp[x*128 + i*2 + 1]);
      const float* ph = Wf + PHH_F + x*48;
#pragma unroll
      for (int k = 0; k < 24; ++k) {
        float cc = ph[2*k], ss = ph[2*k + 1];
        fr[k] += gr*cc + gi*ss;
        fi[k] += gi*cc - gr*ss;
      }
    }
#pragma unroll
    for (int k = 0; k < 24; ++k) {
      pbufA[q*3136 + i*49 + 2*k]     = fr[k];
      pbufA[q*3136 + i*49 + 2*k + 1] = fi[k];
    }
  }
  __syncthreads();
#pragma unroll
  for (int j = 0; j < 12; ++j) {
    int idx = j*256 + t;                      // 3072 = kx*128 + i*2 + part
    int part = idx & 1, i = (idx >> 1) & 63, kx = idx >> 7;
    int m = kx*2 + part;
    Fbuf[idx] = pbufA[i*49 + m] + pbufA[3136 + i*49 + m]
              + pbufA[6272 + i*49 + m] + pbufA[9408 + i*49 + m];
  }
  __syncthreads();
  // B: Fo[kx,o] = sum_i F[kx,i] * W[l][i][o][kx][ky]  (complex, raw layout)
  {
    const int o = t & 63;
    float* FoG = Fo + (size_t)(b*12 + ky)*24*128;
#pragma unroll
    for (int j = 0; j < 6; ++j) {
      int kx = j*4 + (t >> 6);
      const __hip_bfloat16* wselh = (kx < 12) ? w1h : w2h;
      const float*          wself = (kx < 12) ? w1f : w2f;
      int kxe = (kx < 12) ? kx : kx - 12;
      float ar = 0.0f, ai = 0.0f;
      for (int i = 0; i < 64; ++i) {
        float fxr = Fbuf[kx*128 + i*2];
        float fxi = Fbuf[kx*128 + i*2 + 1];
        size_t widx = ((size_t)((l*64 + i)*64 + o))*288 + kxe*24 + ky*2;
        float wr = rdw(wselh, wself, widx, isf32);
        float wi = rdw(wselh, wself, widx + 1, isf32);
        ar += fxr*wr - fxi*wi;
        ai += fxr*wi + fxi*wr;
      }
      FoG[kx*128 + o*2]     = ar;
      FoG[kx*128 + o*2 + 1] = ai;
    }
  }
}

// ---------------- layer: inv-H + inv-W + pointwise + GELU (+ next DFT-W) ----------------
__global__ __launch_bounds__(256) void ky6_layer(const float* Wf,
                                                 __hip_bfloat16* HB,
                                                 __hip_bfloat16* G,
                                                 const float* Fo,
                                                 int l, int last) {
  __shared__ __hip_bfloat16 hrow[16384];   // 32 KB
  __shared__ float pbuf[6400];             // 25.6 KB
  __shared__ float gbuf[1536];             // 6 KB  (g[ky][o][2])
  const int b = blockIdx.x >> 8, x = blockIdx.x & 255;
  const int w = threadIdx.x;
  // (a) per-row inverse-H
  {
    const float* FoG = Fo + (size_t)b*12*24*128;
#pragma unroll
    for (int j = 0; j < 3; ++j) {
      int e = j*256 + w;                   // 768 = ky*64 + o
      int o = e & 63, ky = e >> 6;
      float gr = 0.0f, gi = 0.0f;
#pragma unroll
      for (int kx = 0; kx < 24; ++kx) {
        float cc = Wf[PHH_F + x*48 + 2*kx], ss = Wf[PHH_F + x*48 + 2*kx + 1];
        float fr = FoG[(ky*24 + kx)*128 + o*2];
        float fi = FoG[(ky*24 + kx)*128 + o*2 + 1];
        gr += fr*cc - fi*ss;
        gi += fr*ss + fi*cc;
      }
      gbuf[ky*128 + o*2]     = gr;
      gbuf[ky*128 + o*2 + 1] = gi;
    }
  }
  __syncthreads();
  // (b) inverse rfft along W (DC imag ignored, 2x hermitian, 1/65536)
  float pc[11], ps[11];
#pragma unroll
  for (int k = 0; k < 11; ++k) {
    int idx = (w*(k + 1)) & 255;
    float a = idx * (1.0f/128.0f);
    pc[k] = 2.0f * cospif(a);
    ps[k] = 2.0f * sinpif(a);
  }
  float acc[64];
#pragma unroll
  for (int o = 0; o < 64; ++o) acc[o] = gbuf[o*2];
#pragma unroll
  for (int k = 1; k < 12; ++k) {
#pragma unroll
    for (int o = 0; o < 64; ++o)
      acc[o] += gbuf[k*128 + o*2] * pc[k-1] - gbuf[k*128 + o*2 + 1] * ps[k-1];
  }
  const float* pwb = Wf + PWB_F + l*64;
#pragma unroll
  for (int o = 0; o < 64; ++o) acc[o] = pwb[o] + acc[o] * (1.0f/65536.0f);
  // (c) pointwise conv (h from HB, this thread's own pixel)
  __hip_bfloat16* hb = HB + ((size_t)(b*256 + x)*256 + w)*64;
  const float* pw = Wf + PWF_F + l*4096;
  for (int i = 0; i < 64; ++i) {
    float hv = __bfloat162float(hb[i]);
#pragma unroll
    for (int o = 0; o < 64; ++o) acc[o] += hv * pw[i*64 + o];
  }
  // (d) gelu, store HB (+ LDS row for next DFT)
#pragma unroll
  for (int o = 0; o < 64; ++o) {
    float v = acc[o];
    if (!last) v = 0.5f * v * (1.0f + erff(v * 0.7071067811865475f));
    __hip_bfloat16 vb = __float2bfloat16(v);
    hb[o] = vb;
    hrow[o*256 + ((w + o) & 255)] = vb;
  }
  __syncthreads();
  if (!last) gstep_v6(Wf, G, hrow, pbuf, b, x);
}

// ---------------- head: fc1 + GELU + fc2 -> out (dtype per flag) ----------------
__global__ __launch_bounds__(256) void kh6_head(const float* Wf,
                                                const __hip_bfloat16* HB,
                                                __hip_bfloat16* outH,
                                                float* outF) {
  const int b = blockIdx.x >> 8, x = blockIdx.x & 255;
  const int w = threadIdx.x;
  const int isf32 = (Wf[FLAG_F] != 0.0f);
  const __hip_bfloat16* hb = HB + ((size_t)(b*256 + x)*256 + w)*64;
  float hv[64];
#pragma unroll
  for (int i = 0; i < 64; ++i) hv[i] = __bfloat162float(hb[i]);
  float total = Wf[FC2B_F];
#pragma unroll 1
  for (int half = 0; half < 2; ++half) {
    float acc[64];
#pragma unroll
    for (int o = 0; o < 64; ++o) acc[o] = Wf[FC1B_F + half*64 + o];
    for (int i = 0; i < 64; ++i) {
      float h = hv[i];
#pragma unroll
      for (int o = 0; o < 64; ++o) acc[o] += h * Wf[FC1T_F + i*128 + half*64 + o];
    }
#pragma unroll
    for (int o = 0; o < 64; ++o) {
      float v = acc[o];
      v = 0.5f * v * (1.0f + erff(v * 0.7071067811865475f));
      total += v * Wf[FC2_F + half*64 + o];
    }
  }
  size_t idx = (size_t)(b*256 + x)*256 + w;
  if (isf32) outF[idx] = total;
  else       outH[idx] = __float2bfloat16(total);
}

// ---------------- scan workspace for NaN/inf/huge ----------------
__global__ __launch_bounds__(256) void kc6_scan(float* Wf,
                                                const __hip_bfloat16* HB,
                                                const __hip_bfloat16* G,
                                                const float* Fo) {
  long t0 = (long)blockIdx.x * 256 + threadIdx.x;
  long st = (long)gridDim.x * 256;
  int bt = 0, bg = 0, bf = 0, bh = 0;
  for (long n = t0; n < 43840L; n += st)    { float v = Wf[n];                    if (!(fabsf(v) < 1e8f)) bt = 1; }
  for (long n = t0; n < 3145728L; n += st)  { float v = __bfloat162float(G[n]);   if (!(fabsf(v) < 1e8f)) bg = 1; }
  for (long n = t0; n < 294912L; n += st)   { float v = Fo[n];                    if (!(fabsf(v) < 1e8f)) bf = 1; }
  for (long n = t0; n < 33554432L; n += st) { float v = __bfloat162float(HB[n]);  if (!(fabsf(v) < 1e8f)) bh = 1; }
  if (bt) Wf[SN_T] = 1.0f;
  if (bg) Wf[SN_G] = 1.0f;
  if (bf) Wf[SN_FO] = 1.0f;
  if (bh) Wf[SN_HB] = 1.0f;
}

// ---------------- stage-code reporter (only on failure) ----------------
__global__ __launch_bounds__(256) void kz6_code(const float* Wf, __hip_bfloat16* outH) {
  float code = 0.0f;
  if      (Wf[SN_T]  != 0.0f) code = 18432.0f;
  else if (Wf[SN_G]  != 0.0f) code = 20480.0f;
  else if (Wf[SN_FO] != 0.0f) code = 22528.0f;
  else if (Wf[SN_HB] != 0.0f) code = 24576.0f;
  if (code != 0.0f)
    outH[(size_t)blockIdx.x * 256 + threadIdx.x] = __float2bfloat16(code);
}

// ---------------- launcher ----------------
extern "C" void kernel_launch(void* const* d_in, const int* in_sizes, int n_in,
                              void* d_out, int out_size, void* d_ws, size_t ws_size,
                              hipStream_t stream) {
  (void)out_size;
  __hip_bfloat16* outH = (__hip_bfloat16*)d_out;
  float*          outF = (float*)d_out;
  float*          Wf   = (float*)d_ws;
  __hip_bfloat16* HB   = (__hip_bfloat16*)d_ws + HB_OFF_U;
  __hip_bfloat16* G    = (__hip_bfloat16*)d_ws + G_OFF_U;
  float*          Fo   = (float*)d_ws + FO_OFF_F;

  // host-side sanity: input count/sizes
  static const int EXP_SZ[11] = {524288, 192, 64, 4718592, 4718592,
                                 16384, 256, 8192, 128, 128, 1};
  if (n_in != 11) {
    kf6_fill<<<2048, 256, 0, stream>>>(outH, 27648.0f);
    return;
  }
  for (int i = 0; i < 11; ++i) {
    if (in_sizes[i] != EXP_SZ[i]) {
      kf6_fill<<<2048, 256, 0, stream>>>(outH, 28672.0f + 256.0f * (float)i);
      return;
    }
  }
  if (ws_size < (size_t)WS_NEED) {
    int q = (int)(ws_size >> 25);           // 32MB units
    if (q > 31) q = 31;
    kf6_fill<<<2048, 256, 0, stream>>>(outH, 4096.0f + 32.0f * (float)q);
    return;
  }

  kd6_detect<<<1, 64, 0, stream>>>((const unsigned short*)d_in[0], Wf);
  kt6_tables<<<64, 256, 0, stream>>>(
      (const __hip_bfloat16*)d_in[1], (const float*)d_in[1],
      (const __hip_bfloat16*)d_in[2], (const float*)d_in[2],
      (const __hip_bfloat16*)d_in[5], (const float*)d_in[5],
      (const __hip_bfloat16*)d_in[6], (const float*)d_in[6],
      (const __hip_bfloat16*)d_in[7], (const float*)d_in[7],
      (const __hip_bfloat16*)d_in[8], (const float*)d_in[8],
      (const __hip_bfloat16*)d_in[9], (const float*)d_in[9],
      (const __hip_bfloat16*)d_in[10], (const float*)d_in[10],
      Wf);
  kl6_lift<<<2048, 256, 0, stream>>>((const __hip_bfloat16*)d_in[0],
                                     (const float*)d_in[0], Wf, HB, G);
  for (int l = 0; l < 4; ++l) {
    ks6_spec<<<96, 256, 0, stream>>>(Wf, G,
                                     (const __hip_bfloat16*)d_in[3], (const float*)d_in[3],
                                     (const __hip_bfloat16*)d_in[4], (const float*)d_in[4],
                                     Fo, l);
    ky6_layer<<<2048, 256, 0, stream>>>(Wf, HB, G, Fo, l, (l == 3) ? 1 : 0);
  }
  kh6_head<<<2048, 256, 0, stream>>>(Wf, HB, outH, outF);
  kc6_scan<<<2048, 256, 0, stream>>>(Wf, HB, G, Fo);
  kz6_code<<<2048, 256, 0, stream>>>(Wf, outH);
}

// Round 7
// 2348.197 us; speedup vs baseline: 1.2102x; 1.2102x over previous
//
#include <hip/hip_runtime.h>
#include <hip/hip_bf16.h>

// ---------------- workspace layout v7 (total 74,842,112 bytes) ----------------
// float indices into (float*)d_ws:
#define FC0_F   0        // fc0_w [64][3]
#define FC0B_F  192      // fc0_b [64]
#define PWF_F   256      // pw_w transposed [4][i][o] (16384)
#define PWB_F   16640    // pw_b [4][64]
#define FC1T_F  16896    // fc1_w transposed [64 i][128 f] (8192)
#define FC1B_F  25088    // fc1_b [128]
#define FC2_F   25216    // fc2_w [128]
#define FC2B_F  25344    // fc2_b [1]
#define PHW_F   25408    // phW [256 w][12 ky][2] (6144)
#define PHH_F   31552    // phH [256 x][24 kx][2] (12288) -> end 43840
#define FLAG_F  44032    // 1.0 => inputs f32
// bf16 element indices into (__hip_bfloat16*)d_ws:
#define HB_OFF_U  131072     // h [8][256][256][64]  (33554432 elems)
#define G_OFF_U   33685504   // G [8][256][64][12][2] (3145728 elems)  ** new layout **
// float index for Fo:
#define FO_OFF_F  18415616   // Fo [8][12][24][64][2] f32 (294912)
#define WS_NEED   74842112
#define NTAB 43840

union FU7 { float f; unsigned u; };
__device__ __forceinline__ float bfu2f(unsigned short u) { FU7 v; v.u = ((unsigned)u) << 16; return v.f; }
__device__ __forceinline__ unsigned short f2bfu(float f) {
  FU7 v; v.f = f; unsigned b = v.u;
  return (unsigned short)((b + 0x7FFFu + ((b >> 16) & 1u)) >> 16);   // RNE
}
__device__ __forceinline__ float hunp7(const unsigned* hp, int i) {
  unsigned u = hp[i >> 1];
  return bfu2f((unsigned short)((i & 1) ? (u >> 16) : (u & 0xFFFFu)));
}
__device__ __forceinline__ float gelu7(float v) {
  return 0.5f * v * (1.0f + erff(v * 0.7071067811865475f));
}
__device__ __forceinline__ float rdw7(const __hip_bfloat16* h, const float* f,
                                      long i, int isf32) {
  return isf32 ? f[i] : __bfloat162float(h[i]);
}

// ---------------- fill output with a code (guards only) ----------------
__global__ __launch_bounds__(256) void kf7_fill(__hip_bfloat16* outH, float code) {
  outH[(size_t)blockIdx.x * 256 + threadIdx.x] = __float2bfloat16(code);
}

// ---------------- dtype detect on X ----------------
__global__ __launch_bounds__(64) void kd7_detect(const unsigned short* Xh, float* Wf) {
  if (threadIdx.x == 0 && blockIdx.x == 0) {
    int ok = 1;
    for (int k = 0; k < 128; ++k) {
      unsigned short u = Xh[2 * k];
      unsigned e = (u >> 7) & 0xFF;
      if (!(u == 0 || (e >= 0x60 && e <= 0x88))) ok = 0;
    }
    Wf[FLAG_F] = ok ? 0.0f : 1.0f;
  }
}

// ---------------- tables ----------------
__global__ __launch_bounds__(256) void kt7_tables(
    const __hip_bfloat16* f0h, const float* f0f,
    const __hip_bfloat16* f0bh, const float* f0bf,
    const __hip_bfloat16* pwh, const float* pwf,
    const __hip_bfloat16* pwbh, const float* pwbf,
    const __hip_bfloat16* f1h, const float* f1f,
    const __hip_bfloat16* f1bh, const float* f1bf,
    const __hip_bfloat16* f2h, const float* f2f,
    const __hip_bfloat16* f2bh, const float* f2bf,
    float* Wf) {
  const int isf32 = (Wf[FLAG_F] != 0.0f);
  const int stride = gridDim.x * blockDim.x;
  for (int n0 = blockIdx.x * blockDim.x + threadIdx.x; n0 < NTAB; n0 += stride) {
    int n = n0;
    if (n < 192) { Wf[FC0_F + n] = rdw7(f0h, f0f, n, isf32); continue; }
    n -= 192;
    if (n < 64)  { Wf[FC0B_F + n] = rdw7(f0bh, f0bf, n, isf32); continue; }
    n -= 64;
    if (n < 16384) { int l = n >> 12, i = (n >> 6) & 63, o = n & 63;
      Wf[PWF_F + n] = rdw7(pwh, pwf, (l*64 + o)*64 + i, isf32); continue; }
    n -= 16384;
    if (n < 256) { Wf[PWB_F + n] = rdw7(pwbh, pwbf, n, isf32); continue; }
    n -= 256;
    if (n < 8192) { int i = n >> 7, f = n & 127;
      Wf[FC1T_F + n] = rdw7(f1h, f1f, f*64 + i, isf32); continue; }
    n -= 8192;
    if (n < 128) { Wf[FC1B_F + n] = rdw7(f1bh, f1bf, n, isf32); continue; }
    n -= 128;
    if (n < 128) { Wf[FC2_F + n] = rdw7(f2h, f2f, n, isf32); continue; }
    n -= 128;
    if (n < 1)   { Wf[FC2B_F + n] = rdw7(f2bh, f2bf, 0, isf32); continue; }
    n -= 1;
    if (n < 6144) { int w = n / 24, r = n % 24, ky = r >> 1, part = r & 1;
      int idx = (w * ky) & 255; float a = idx * (1.0f/128.0f);
      Wf[PHW_F + n] = part ? sinpif(a) : cospif(a); continue; }
    n -= 6144;
    { int x = n / 48, r = n % 48, kx = r >> 1, part = r & 1;
      int kxa = (kx < 12) ? kx : kx + 232;          // 244..255 = negative H rows
      int idx = (x * kxa) & 255; float a = idx * (1.0f/128.0f);
      Wf[PHH_F + n] = part ? sinpif(a) : cospif(a); }
  }
}

// ---------------- forward DFT along W of the LDS row -> G (linear writes) ----------------
// hrow (ushort, swizzled): hrow[c*256 + ((w+c)&255)] ; pbuf ALIASES hrow (barriers separate)
__device__ void gstep7(const float* Wf, __hip_bfloat16* G,
                       unsigned short* hrow, float* pbuf, int b, int x) {
  const int t = threadIdx.x;
  const int c = t & 63, q = t >> 6;
  float aR[12], aI[12];
#pragma unroll
  for (int k = 0; k < 12; ++k) { aR[k] = 0.0f; aI[k] = 0.0f; }
  for (int j = 0; j < 64; ++j) {
    int w = q*64 + j;                            // wave-uniform
    float hv = bfu2f(hrow[c*256 + ((w + c) & 255)]);
    const float* ph = Wf + PHW_F + w*24;
#pragma unroll
    for (int k = 0; k < 12; ++k) {
      aR[k] += hv * ph[2*k];
      aI[k] -= hv * ph[2*k + 1];
    }
  }
  __syncthreads();                               // hrow reads complete; pbuf may overwrite
#pragma unroll
  for (int k = 0; k < 12; ++k) {
    pbuf[q*1600 + c*25 + 2*k]     = aR[k];
    pbuf[q*1600 + c*25 + 2*k + 1] = aI[k];
  }
  __syncthreads();
  // G row [i][ky][2] = 1536 contiguous bf16 -> 768 u32 linear stores
  unsigned* Grow = (unsigned*)((unsigned short*)G + (size_t)(b*256 + x)*1536);
#pragma unroll
  for (int j = 0; j < 3; ++j) {
    int p = j*256 + t;                 // pair index; elem = 2p = cc*24 + m
    int cc = p / 12;
    int m0 = 2*p - cc*24;
    float s0 = pbuf[cc*25 + m0]     + pbuf[1600 + cc*25 + m0]
             + pbuf[3200 + cc*25 + m0]     + pbuf[4800 + cc*25 + m0];
    float s1 = pbuf[cc*25 + m0 + 1] + pbuf[1600 + cc*25 + m0 + 1]
             + pbuf[3200 + cc*25 + m0 + 1] + pbuf[4800 + cc*25 + m0 + 1];
    Grow[p] = (unsigned)f2bfu(s0) | ((unsigned)f2bfu(s1) << 16);
  }
}

// ---------------- lift: fc0 -> HB(packed) + LDS row, DFT-W -> G ----------------
__global__ __launch_bounds__(256) void kl7_lift(const __hip_bfloat16* Xh, const float* Xf,
                                                const float* Wf,
                                                __hip_bfloat16* HB, __hip_bfloat16* G) {
  __shared__ __align__(16) char smem[32768];     // hrow 32KB; pbuf aliases
  unsigned short* hrow = (unsigned short*)smem;
  float* pbuf = (float*)smem;
  const int b = blockIdx.x >> 8, x = blockIdx.x & 255;
  const int w = threadIdx.x;
  const int isf32 = (Wf[FLAG_F] != 0.0f);
  float xv = isf32 ? Xf[(size_t)(b*256 + x)*256 + w]
                   : __bfloat162float(Xh[(size_t)(b*256 + x)*256 + w]);
  float gx = x * (1.0f/255.0f), gy = w * (1.0f/255.0f);
  uint4* hbu = (uint4*)(HB + ((size_t)(b*256 + x)*256 + w)*64);
#pragma unroll
  for (int c0 = 0; c0 < 8; ++c0) {
    unsigned pk[4];
#pragma unroll
    for (int n = 0; n < 4; ++n) {
      int c = c0*8 + n*2;
      float h0 = xv*Wf[FC0_F + c*3]     + gx*Wf[FC0_F + c*3 + 1]
               + gy*Wf[FC0_F + c*3 + 2] + Wf[FC0B_F + c];
      float h1 = xv*Wf[FC0_F + c*3 + 3] + gx*Wf[FC0_F + c*3 + 4]
               + gy*Wf[FC0_F + c*3 + 5] + Wf[FC0B_F + c + 1];
      unsigned short b0 = f2bfu(h0), b1 = f2bfu(h1);
      hrow[c*256 + ((w + c) & 255)]           = b0;
      hrow[(c+1)*256 + ((w + c + 1) & 255)]   = b1;
      pk[n] = (unsigned)b0 | ((unsigned)b1 << 16);
    }
    hbu[c0] = make_uint4(pk[0], pk[1], pk[2], pk[3]);
  }
  __syncthreads();
  gstep7(Wf, G, hrow, pbuf, b, x);
}

// ---------------- spectral: block=(b,kx); DFT-H + channel mix -> Fo ----------------
__global__ __launch_bounds__(256) void ks7_spec(const float* Wf, const __hip_bfloat16* G,
    const __hip_bfloat16* w1h, const float* w1f,
    const __hip_bfloat16* w2h, const float* w2f,
    float* Fo, int l) {
  __shared__ float pbufA[6400];    // A partials [q][i][25] / B partials [q][ky*128+o*2+p]
  __shared__ float Fbuf[1536];     // F [i][24]  (ky pairs)
  const int b = blockIdx.x / 24, kx = blockIdx.x % 24;
  const int t = threadIdx.x;
  const int isf32 = (Wf[FLAG_F] != 0.0f);
  // A: F[i][ky] = sum_x G[b][x][i][ky] * e^{-i 2pi x kxa/256}
  {
    const int i = t & 63, q = t >> 6;
    float fr[12], fi[12];
#pragma unroll
    for (int k = 0; k < 12; ++k) { fr[k] = 0.0f; fi[k] = 0.0f; }
    for (int j = 0; j < 64; ++j) {
      int x = q*64 + j;                          // wave-uniform
      const uint4* gp = (const uint4*)((const unsigned short*)G
                        + (size_t)(b*256 + x)*1536 + i*24);
      uint4 u0 = gp[0], u1 = gp[1], u2 = gp[2];
      float cc = Wf[PHH_F + x*48 + 2*kx], ss = Wf[PHH_F + x*48 + 2*kx + 1];
      unsigned uu[12] = {u0.x, u0.y, u0.z, u0.w, u1.x, u1.y, u1.z, u1.w,
                         u2.x, u2.y, u2.z, u2.w};
#pragma unroll
      for (int k = 0; k < 12; ++k) {
        float gr = bfu2f((unsigned short)(uu[k] & 0xFFFFu));
        float gi = bfu2f((unsigned short)(uu[k] >> 16));
        fr[k] += gr*cc + gi*ss;
        fi[k] += gi*cc - gr*ss;
      }
    }
#pragma unroll
    for (int k = 0; k < 12; ++k) {
      pbufA[q*1600 + i*25 + 2*k]     = fr[k];
      pbufA[q*1600 + i*25 + 2*k + 1] = fi[k];
    }
  }
  __syncthreads();
#pragma unroll
  for (int j = 0; j < 6; ++j) {
    int idx = j*256 + t;                         // 1536 = i*24 + m
    int cc = idx / 24, m = idx - cc*24;
    Fbuf[idx] = pbufA[cc*25 + m] + pbufA[1600 + cc*25 + m]
              + pbufA[3200 + cc*25 + m] + pbufA[4800 + cc*25 + m];
  }
  __syncthreads();
  // B: Fo[ky][o] = sum_i F[i][ky] * W[l][i][o][kx][ky]  (12 contiguous ky-pairs per (i,o))
  {
    const int o = t & 63, q = t >> 6;
    float br[12], bi[12];
#pragma unroll
    for (int k = 0; k < 12; ++k) { br[k] = 0.0f; bi[k] = 0.0f; }
    const int kxe = (kx < 12) ? kx : kx - 12;
    const __hip_bfloat16* wh = (kx < 12) ? w1h : w2h;
    const float*         wfp = (kx < 12) ? w1f : w2f;
    for (int i = q*16; i < q*16 + 16; ++i) {
      size_t widx = ((size_t)((l*64 + i)*64 + o))*288 + (size_t)kxe*24;
      float wr_[12], wi_[12];
      if (isf32) {
        const float* wp = wfp + widx;
#pragma unroll
        for (int k = 0; k < 12; ++k) { wr_[k] = wp[2*k]; wi_[k] = wp[2*k + 1]; }
      } else {
        const uint4* wp = (const uint4*)((const unsigned short*)wh + widx);
        uint4 u0 = wp[0], u1 = wp[1], u2 = wp[2];
        unsigned uu[12] = {u0.x, u0.y, u0.z, u0.w, u1.x, u1.y, u1.z, u1.w,
                           u2.x, u2.y, u2.z, u2.w};
#pragma unroll
        for (int k = 0; k < 12; ++k) {
          wr_[k] = bfu2f((unsigned short)(uu[k] & 0xFFFFu));
          wi_[k] = bfu2f((unsigned short)(uu[k] >> 16));
        }
      }
      const float* Fp = Fbuf + i*24;
#pragma unroll
      for (int k = 0; k < 12; ++k) {
        float Fr = Fp[2*k], Fi = Fp[2*k + 1];    // LDS broadcast (i wave-uniform)
        br[k] += Fr*wr_[k] - Fi*wi_[k];
        bi[k] += Fr*wi_[k] + Fi*wr_[k];
      }
    }
#pragma unroll
    for (int k = 0; k < 12; ++k) {
      pbufA[q*1536 + k*128 + o*2]     = br[k];
      pbufA[q*1536 + k*128 + o*2 + 1] = bi[k];
    }
  }
  __syncthreads();
#pragma unroll
  for (int j = 0; j < 6; ++j) {
    int n = j*256 + t;                           // 1536 = ky*128 + o*2 + p
    int ky = n >> 7, r = n & 127;
    Fo[((size_t)(b*12 + ky)*24 + kx)*128 + r] =
        pbufA[n] + pbufA[1536 + n] + pbufA[3072 + n] + pbufA[4608 + n];
  }
}

// ---------------- layer: inv-H + inv-W + pointwise + GELU (+ next DFT-W) ----------------
__global__ __launch_bounds__(256, 4) void ky7_layer(const float* Wf,
                                                    __hip_bfloat16* HB,
                                                    __hip_bfloat16* G,
                                                    const float* Fo,
                                                    int l, int last) {
  __shared__ __align__(16) char smem[38912];     // hrow 32KB (alias pbuf 25.6KB) + gbuf 6KB
  unsigned short* hrow = (unsigned short*)smem;
  float* pbuf = (float*)smem;
  float* gbuf = (float*)(smem + 32768);          // [ky][o][2] 1536 floats
  const int b = blockIdx.x >> 8, x = blockIdx.x & 255;
  const int w = threadIdx.x;
  // packed h for this pixel (issue loads early)
  unsigned hp[32];
  {
    const uint4* hbu = (const uint4*)(HB + ((size_t)(b*256 + x)*256 + w)*64);
#pragma unroll
    for (int j = 0; j < 8; ++j) {
      uint4 v = hbu[j];
      hp[j*4] = v.x; hp[j*4+1] = v.y; hp[j*4+2] = v.z; hp[j*4+3] = v.w;
    }
  }
  // (a) per-row inverse-H -> gbuf
  {
    const float* FoG = Fo + (size_t)b*12*24*128;
    const float* phx = Wf + PHH_F + x*48;
#pragma unroll
    for (int j = 0; j < 3; ++j) {
      int e = j*256 + w;                         // 768 = ky*64 + o
      int o = e & 63, ky = e >> 6;
      float gr = 0.0f, gi = 0.0f;
#pragma unroll
      for (int kx = 0; kx < 24; ++kx) {
        float cc = phx[2*kx], ss = phx[2*kx + 1];
        float fr = FoG[(ky*24 + kx)*128 + o*2];
        float fi = FoG[(ky*24 + kx)*128 + o*2 + 1];
        gr += fr*cc - fi*ss;
        gi += fr*ss + fi*cc;
      }
      gbuf[ky*128 + o*2]     = gr;
      gbuf[ky*128 + o*2 + 1] = gi;
    }
  }
  __syncthreads();
  // (b,c,d) two halves of 32 output channels (keeps VGPR <= 128 for 4 blocks/CU)
  float pc[11], ps[11];
#pragma unroll
  for (int k = 0; k < 11; ++k) {
    int idx = (w*(k + 1)) & 255;
    float a = idx * (1.0f/128.0f);
    pc[k] = 2.0f * cospif(a);
    ps[k] = 2.0f * sinpif(a);
  }
  const float* pw  = Wf + PWF_F + l*4096;
  const float* pwb = Wf + PWB_F + l*64;
  uint4* hbw = (uint4*)(HB + ((size_t)(b*256 + x)*256 + w)*64);
#pragma unroll 1
  for (int half = 0; half < 2; ++half) {
    const int o0 = half*32;
    float acc[32];
#pragma unroll
    for (int oo = 0; oo < 32; ++oo) acc[oo] = gbuf[(o0 + oo)*2];
#pragma unroll
    for (int k = 1; k < 12; ++k) {
#pragma unroll
      for (int oo = 0; oo < 32; ++oo)
        acc[oo] += gbuf[k*128 + (o0 + oo)*2] * pc[k-1]
                 - gbuf[k*128 + (o0 + oo)*2 + 1] * ps[k-1];
    }
#pragma unroll
    for (int oo = 0; oo < 32; ++oo) acc[oo] = pwb[o0 + oo] + acc[oo] * (1.0f/65536.0f);
    for (int i = 0; i < 64; ++i) {
      float hv = hunp7(hp, i);
#pragma unroll
      for (int oo = 0; oo < 32; ++oo) acc[oo] += hv * pw[i*64 + o0 + oo];
    }
#pragma unroll
    for (int j = 0; j < 4; ++j) {
      unsigned pk[4];
#pragma unroll
      for (int n = 0; n < 4; ++n) {
        int oo = j*8 + n*2;
        float v0 = acc[oo], v1 = acc[oo + 1];
        if (!last) { v0 = gelu7(v0); v1 = gelu7(v1); }
        unsigned short b0 = f2bfu(v0), b1 = f2bfu(v1);
        hrow[(o0 + oo)*256 + ((w + o0 + oo) & 255)]         = b0;
        hrow[(o0 + oo + 1)*256 + ((w + o0 + oo + 1) & 255)] = b1;
        pk[n] = (unsigned)b0 | ((unsigned)b1 << 16);
      }
      hbw[half*4 + j] = make_uint4(pk[0], pk[1], pk[2], pk[3]);
    }
  }
  __syncthreads();
  if (!last) gstep7(Wf, G, hrow, pbuf, b, x);
}

// ---------------- head: fc1 + GELU + fc2 -> out ----------------
__global__ __launch_bounds__(256, 4) void kh7_head(const float* Wf,
                                                   const __hip_bfloat16* HB,
                                                   __hip_bfloat16* outH, float* outF) {
  const int b = blockIdx.x >> 8, x = blockIdx.x & 255;
  const int w = threadIdx.x;
  const int isf32 = (Wf[FLAG_F] != 0.0f);
  unsigned hp[32];
  {
    const uint4* hbu = (const uint4*)(HB + ((size_t)(b*256 + x)*256 + w)*64);
#pragma unroll
    for (int j = 0; j < 8; ++j) {
      uint4 v = hbu[j];
      hp[j*4] = v.x; hp[j*4+1] = v.y; hp[j*4+2] = v.z; hp[j*4+3] = v.w;
    }
  }
  float total = Wf[FC2B_F];
#pragma unroll 1
  for (int half = 0; half < 2; ++half) {
    float acc[64];
#pragma unroll
    for (int o = 0; o < 64; ++o) acc[o] = Wf[FC1B_F + half*64 + o];
    for (int i = 0; i < 64; ++i) {
      float hv = hunp7(hp, i);
#pragma unroll
      for (int o = 0; o < 64; ++o) acc[o] += hv * Wf[FC1T_F + i*128 + half*64 + o];
    }
#pragma unroll
    for (int o = 0; o < 64; ++o)
      total += gelu7(acc[o]) * Wf[FC2_F + half*64 + o];
  }
  size_t idx = (size_t)(b*256 + x)*256 + w;
  if (isf32) outF[idx] = total;
  else       outH[idx] = __float2bfloat16(total);
}

// ---------------- launcher ----------------
extern "C" void kernel_launch(void* const* d_in, const int* in_sizes, int n_in,
                              void* d_out, int out_size, void* d_ws, size_t ws_size,
                              hipStream_t stream) {
  (void)out_size;
  __hip_bfloat16* outH = (__hip_bfloat16*)d_out;
  float*          outF = (float*)d_out;
  float*          Wf   = (float*)d_ws;
  __hip_bfloat16* HB   = (__hip_bfloat16*)d_ws + HB_OFF_U;
  __hip_bfloat16* G    = (__hip_bfloat16*)d_ws + G_OFF_U;
  float*          Fo   = (float*)d_ws + FO_OFF_F;

  static const int EXP_SZ[11] = {524288, 192, 64, 4718592, 4718592,
                                 16384, 256, 8192, 128, 128, 1};
  if (n_in != 11) { kf7_fill<<<2048, 256, 0, stream>>>(outH, 27648.0f); return; }
  for (int i = 0; i < 11; ++i) {
    if (in_sizes[i] != EXP_SZ[i]) {
      kf7_fill<<<2048, 256, 0, stream>>>(outH, 28672.0f + 256.0f * (float)i);
      return;
    }
  }
  if (ws_size < (size_t)WS_NEED) {
    int q = (int)(ws_size >> 25); if (q > 31) q = 31;
    kf7_fill<<<2048, 256, 0, stream>>>(outH, 4096.0f + 32.0f * (float)q);
    return;
  }

  kd7_detect<<<1, 64, 0, stream>>>((const unsigned short*)d_in[0], Wf);
  kt7_tables<<<64, 256, 0, stream>>>(
      (const __hip_bfloat16*)d_in[1], (const float*)d_in[1],
      (const __hip_bfloat16*)d_in[2], (const float*)d_in[2],
      (const __hip_bfloat16*)d_in[5], (const float*)d_in[5],
      (const __hip_bfloat16*)d_in[6], (const float*)d_in[6],
      (const __hip_bfloat16*)d_in[7], (const float*)d_in[7],
      (const __hip_bfloat16*)d_in[8], (const float*)d_in[8],
      (const __hip_bfloat16*)d_in[9], (const float*)d_in[9],
      (const __hip_bfloat16*)d_in[10], (const float*)d_in[10],
      Wf);
  kl7_lift<<<2048, 256, 0, stream>>>((const __hip_bfloat16*)d_in[0],
                                     (const float*)d_in[0], Wf, HB, G);
  for (int l = 0; l < 4; ++l) {
    ks7_spec<<<192, 256, 0, stream>>>(Wf, G,
        (const __hip_bfloat16*)d_in[3], (const float*)d_in[3],
        (const __hip_bfloat16*)d_in[4], (const float*)d_in[4],
        Fo, l);
    ky7_layer<<<2048, 256, 0, stream>>>(Wf, HB, G, Fo, l, (l == 3) ? 1 : 0);
  }
  kh7_head<<<2048, 256, 0, stream>>>(Wf, HB, outH, outF);
}